// Round 3
// baseline (2303.372 us; speedup 1.0000x reference)
//
#include <hip/hip_runtime.h>
#include <math.h>

// AttentionBlock: trace-std norm -> qkv (w_in) -> per-(n,h) 4x4-block attention
// with matrix-exponential "softmax" -> w_out -> residual, all fp32.
// N=128, E=64, HID=256, L=4, NH=8, dh=32.
//
// ws layout (floats):
//   winT  [256][768]  = w_in^T      (196608)
//   woutT [256][256]  = w_out^T     (65536)
//   Q,K,V [n][h][e|f][d][p] p=a*4+b (3 x 33554432)
// Y (out_heads, [n][e][h*32+d][a*4+c]) lives in d_out (overwritten by k_out).

#define QKV_SZ   33554432u
#define OF_WINT  0u
#define OF_WOUTT 196608u
#define OF_Q     262144u
#define OF_K     (OF_Q + QKV_SZ)
#define OF_V     (OF_K + QKV_SZ)
#define WS_FLOATS (OF_V + QKV_SZ)

// LDS padding for k_attn (bank analysis in comments below).
#define QP  20    // q_l d-stride
#define QES 656   // q_l e-stride = 32*20+16 ; mod 32 == 16
#define KP  20    // k_l/v_l d-stride
#define KGS 648   // k_l/v_l f-stride = 32*20+8 ; mod 32 == 8
#define EPS_W 272 // exps per-wave stride
#define EPS_E 68  // exps per-e stride

__global__ __launch_bounds__(256) void k_prep(const float* __restrict__ w_in,
                                              const float* __restrict__ w_out,
                                              float* __restrict__ winT,
                                              float* __restrict__ woutT) {
    int idx = blockIdx.x * 256 + threadIdx.x;
    if (idx < 768 * 256) {
        int o = idx >> 8, c = idx & 255;
        winT[c * 768 + o] = w_in[idx];
    }
    if (idx < 256 * 256) {
        int o = idx >> 8, c = idx & 255;
        woutT[c * 256 + o] = w_out[idx];
    }
}

// One block per (n,e): fused trace-std norm + QKV projection.
// GEMM tiling: thread = (pg = t&3, og = t>>2) owns p in [pg*4,pg*4+4),
// o in [og*12, og*12+12). Per c: 1 broadcast ds_read_b128 (x) + 3 float4
// global loads (w) -> 48 FMA. VALU-bound; w L2 traffic 1x (~6.3 GB total).
__global__ __launch_bounds__(256) void k_qkv(const float* __restrict__ in,
        const float* __restrict__ winT, const float* __restrict__ rms,
        float* __restrict__ Q, float* __restrict__ Kb, float* __restrict__ Vb) {
    __shared__ __align__(16) float x_l[4096];   // [c][p]
    __shared__ float red[8];
    int b = blockIdx.x;               // n*64+e
    int nn = b >> 6, e = b & 63;
    int t = threadIdx.x;
    int w = t >> 6, lane = t & 63;
    const float* src = in + (size_t)b * 4096;

    #pragma unroll
    for (int q = 0; q < 4; ++q)
        *(float4*)(x_l + t * 16 + q * 4) = *(const float4*)(src + t * 16 + q * 4);
    __syncthreads();

    // per-channel trace of raw input (diag of 4x4), then sample std (ddof=1)
    float tr = x_l[t*16] + x_l[t*16+5] + x_l[t*16+10] + x_l[t*16+15];
    float s = tr;
    #pragma unroll
    for (int o = 1; o < 64; o <<= 1) s += __shfl_xor(s, o);
    if (lane == 0) red[w] = s;
    __syncthreads();
    float mean = (red[0] + red[1] + red[2] + red[3]) * (1.0f / 256.0f);
    float dv = tr - mean; dv *= dv;
    #pragma unroll
    for (int o = 1; o < 64; o <<= 1) dv += __shfl_xor(dv, o);
    if (lane == 0) red[4 + w] = dv;
    __syncthreads();
    float var = (red[4] + red[5] + red[6] + red[7]) * (1.0f / 255.0f);
    float sc = rms[t] / (sqrtf(var) + 1e-8f);

    #pragma unroll
    for (int q = 0; q < 4; ++q) {
        float4 v4 = *(float4*)(x_l + t*16 + q*4);
        v4.x *= sc; v4.y *= sc; v4.z *= sc; v4.w *= sc;
        *(float4*)(x_l + t*16 + q*4) = v4;
    }
    __syncthreads();

    int pg = t & 3, og = t >> 2;
    float acc[12][4];
    #pragma unroll
    for (int j = 0; j < 12; ++j)
        #pragma unroll
        for (int i = 0; i < 4; ++i) acc[j][i] = 0.f;

    const float* wrow = winT + og * 12;
    #pragma unroll 2
    for (int c = 0; c < 256; ++c) {
        float4 x4 = *(const float4*)(x_l + c * 16 + pg * 4);   // broadcast
        float wv[12];
        *(float4*)(wv + 0) = *(const float4*)(wrow + c * 768 + 0);
        *(float4*)(wv + 4) = *(const float4*)(wrow + c * 768 + 4);
        *(float4*)(wv + 8) = *(const float4*)(wrow + c * 768 + 8);
        #pragma unroll
        for (int j = 0; j < 12; ++j) {
            float wj = wv[j];
            acc[j][0] += x4.x * wj; acc[j][1] += x4.y * wj;
            acc[j][2] += x4.z * wj; acc[j][3] += x4.w * wj;
        }
    }

    #pragma unroll
    for (int j = 0; j < 12; ++j) {
        int o = og * 12 + j;
        int buf = o >> 8, co = o & 255;
        int h = co >> 5, d = co & 31;
        float* dst = (buf == 0) ? Q : (buf == 1) ? Kb : Vb;
        size_t ad = (((size_t)(nn * 8 + h)) * 64 + e) * 512 + d * 16 + pg * 4;
        *(float4*)(dst + ad) = make_float4(acc[j][0], acc[j][1], acc[j][2], acc[j][3]);
    }
}

// One block per (n,h,e-16-chunk). Wave w owns e = e0 + w*4 + {0..3}.
// Per f-group of 4: lane (rep,ee,g) computes the FULL 4x4 qk for (e,f) over
// d = dd*4+rep, rep-reduces via shfl_xor, then exponentiates its matrix fully
// in registers, writes masked exp to LDS; all lanes (d_o,half) accumulate O.
// K/V for fg+1 prefetched into registers right after the ds_write of fg
// (T14 async-stage: full compute phase covers the global latency).
__global__ __launch_bounds__(256) void k_attn(const float* __restrict__ Q,
        const float* __restrict__ Kg, const float* __restrict__ Vg,
        const float* __restrict__ rmask, float* __restrict__ Y) {
    __shared__ __align__(16) float q_l[16 * QES];   // 41 KB
    __shared__ __align__(16) float k_l[4 * KGS];    // 10.1 KB
    __shared__ __align__(16) float v_l[4 * KGS];    // 10.1 KB
    __shared__ __align__(16) float exps_l[4 * EPS_W];

    // bijective remap: 4 consecutive logical blocks (same (n,h)) on one XCD
    int lb = ((blockIdx.x & 7) << 9) | (blockIdx.x >> 3);
    int eq = lb & 3, h = (lb >> 2) & 7, nn = lb >> 5;
    int tid = threadIdx.x;
    int w = tid >> 6, lane = tid & 63;
    size_t nhbase = ((size_t)(nn * 8 + h)) * (64 * 512);
    int e0 = eq * 16;

    const float rsq = 0.17677669529663687f;  // 1/sqrt(32)

    // stage q for 16 e's (pre-scaled by 1/sqrt(dh)) into padded layout
    #pragma unroll
    for (int r = 0; r < 8; ++r) {
        int idx = r * 256 + tid;              // float4 index
        int ee = idx >> 7, rem = idx & 127;
        int d = rem >> 2, c4 = rem & 3;
        float4 v4 = *(const float4*)(Q + nhbase + (size_t)(e0 + ee) * 512 + d * 16 + c4 * 4);
        v4.x *= rsq; v4.y *= rsq; v4.z *= rsq; v4.w *= rsq;
        *(float4*)(q_l + ee * QES + d * QP + c4 * 4) = v4;
    }

    int rep = lane >> 4, ee = (lane >> 2) & 3, g = lane & 3;
    int eL = w * 4 + ee;
    int d_o = lane & 31, half = lane >> 5;

    float acc[4][2][4];
    #pragma unroll
    for (int a = 0; a < 4; ++a)
        #pragma unroll
        for (int x = 0; x < 2; ++x)
            #pragma unroll
            for (int c = 0; c < 4; ++c) acc[a][x][c] = 0.f;
    float dtr = 0.f;

    // prologue: prefetch fg=0 K/V into registers
    float4 pk[2], pv[2];
    #pragma unroll
    for (int r = 0; r < 2; ++r) {
        int slot = r * 256 + tid;
        int gg = slot >> 7, rem = slot & 127;
        int d = rem >> 2, c4 = rem & 3;
        size_t goff = nhbase + (size_t)gg * 512 + d * 16 + c4 * 4;
        pk[r] = *(const float4*)(Kg + goff);
        pv[r] = *(const float4*)(Vg + goff);
    }

    for (int fg = 0; fg < 16; ++fg) {
        __syncthreads();                      // (a) prior attV reads done
        #pragma unroll
        for (int r = 0; r < 2; ++r) {         // write prefetched k/v to LDS
            int slot = r * 256 + tid;
            int gg = slot >> 7, rem = slot & 127;
            int d = rem >> 2, c4 = rem & 3;
            *(float4*)(k_l + gg * KGS + d * KP + c4 * 4) = pk[r];
            *(float4*)(v_l + gg * KGS + d * KP + c4 * 4) = pv[r];
        }
        __syncthreads();                      // (b) k_l/v_l ready
        if (fg < 15) {                        // prefetch fg+1 (regs now free)
            #pragma unroll
            for (int r = 0; r < 2; ++r) {
                int slot = r * 256 + tid;
                int gg = slot >> 7, rem = slot & 127;
                int d = rem >> 2, c4 = rem & 3;
                size_t goff = nhbase + (size_t)((fg + 1) * 4 + gg) * 512 + d * 16 + c4 * 4;
                pk[r] = *(const float4*)(Kg + goff);
                pv[r] = *(const float4*)(Vg + goff);
            }
        }

        // qk[a][c] = sum_{d,b} q[e][d][a*4+b] * k[f][d][b*4+c], d-split by rep
        float m[16];
        #pragma unroll
        for (int t = 0; t < 16; ++t) m[t] = 0.f;
        {
            const float* qp = q_l + eL * QES + rep * QP;
            const float* kp = k_l + g * KGS + rep * KP;
            #pragma unroll 2
            for (int dd = 0; dd < 8; ++dd) {
                float qa[16], kb[16];
                const float* qd = qp + dd * (4 * QP);
                const float* kd = kp + dd * (4 * KP);
                *(float4*)(qa + 0)  = *(const float4*)(qd + 0);
                *(float4*)(qa + 4)  = *(const float4*)(qd + 4);
                *(float4*)(qa + 8)  = *(const float4*)(qd + 8);
                *(float4*)(qa + 12) = *(const float4*)(qd + 12);
                *(float4*)(kb + 0)  = *(const float4*)(kd + 0);
                *(float4*)(kb + 4)  = *(const float4*)(kd + 4);
                *(float4*)(kb + 8)  = *(const float4*)(kd + 8);
                *(float4*)(kb + 12) = *(const float4*)(kd + 12);
                #pragma unroll
                for (int a = 0; a < 4; ++a)
                    #pragma unroll
                    for (int bb = 0; bb < 4; ++bb)
                        #pragma unroll
                        for (int c = 0; c < 4; ++c)
                            m[a*4+c] += qa[a*4+bb] * kb[bb*4+c];
            }
        }
        #pragma unroll
        for (int t = 0; t < 16; ++t) {        // reduce over rep (lane bits 4,5)
            m[t] += __shfl_xor(m[t], 16);
            m[t] += __shfl_xor(m[t], 32);
        }

        // ---- register-local 4x4 expm: scaling & squaring + Taylor-8 ----
        float r0 = fabsf(m[0])  + fabsf(m[1])  + fabsf(m[2])  + fabsf(m[3]);
        float r1 = fabsf(m[4])  + fabsf(m[5])  + fabsf(m[6])  + fabsf(m[7]);
        float r2 = fabsf(m[8])  + fabsf(m[9])  + fabsf(m[10]) + fabsf(m[11]);
        float r3 = fabsf(m[12]) + fabsf(m[13]) + fabsf(m[14]) + fabsf(m[15]);
        float nrm = fmaxf(fmaxf(r0, r1), fmaxf(r2, r3));
        int sq = 0;
        if (nrm > 0.5f) {
            sq = (int)ceilf(log2f(nrm)) + 1;   // 2^-sq * nrm <= 0.5
            if (sq < 0) sq = 0;
        }
        float sc2 = exp2f((float)(-sq));
        #pragma unroll
        for (int t = 0; t < 16; ++t) m[t] *= sc2;
        float p[16];
        #pragma unroll
        for (int t = 0; t < 16; ++t) p[t] = 0.f;
        p[0] = p[5] = p[10] = p[15] = 1.f;
        #pragma unroll
        for (int tt = 8; tt >= 1; --tt) {      // Horner: p = I + (m@p)/tt
            float np[16];
            float rr = 1.0f / (float)tt;
            #pragma unroll
            for (int i = 0; i < 4; ++i)
                #pragma unroll
                for (int j = 0; j < 4; ++j) {
                    float s2 = m[i*4+0]*p[j] + m[i*4+1]*p[4+j] + m[i*4+2]*p[8+j] + m[i*4+3]*p[12+j];
                    np[i*4+j] = ((i == j) ? 1.0f : 0.0f) + s2 * rr;
                }
            #pragma unroll
            for (int t = 0; t < 16; ++t) p[t] = np[t];
        }
        for (int it = 0; it < sq; ++it) {      // divergent squaring, reg-local
            float np[16];
            #pragma unroll
            for (int i = 0; i < 4; ++i)
                #pragma unroll
                for (int j = 0; j < 4; ++j)
                    np[i*4+j] = p[i*4+0]*p[j] + p[i*4+1]*p[4+j] + p[i*4+2]*p[8+j] + p[i*4+3]*p[12+j];
            #pragma unroll
            for (int t = 0; t < 16; ++t) p[t] = np[t];
        }

        dtr += p[0] + p[5] + p[10] + p[15];    // pre-mask trace, summed over f

        float mk = rmask[nn * 64 + fg * 4 + g];
        if (rep == 0) {                        // one replica writes masked exp
            float* eb = exps_l + w * EPS_W + ee * EPS_E + g * 16;
            *(float4*)(eb + 0)  = make_float4(p[0]*mk,  p[1]*mk,  p[2]*mk,  p[3]*mk);
            *(float4*)(eb + 4)  = make_float4(p[4]*mk,  p[5]*mk,  p[6]*mk,  p[7]*mk);
            *(float4*)(eb + 8)  = make_float4(p[8]*mk,  p[9]*mk,  p[10]*mk, p[11]*mk);
            *(float4*)(eb + 12) = make_float4(p[12]*mk, p[13]*mk, p[14]*mk, p[15]*mk);
        }
        // wave-internal in-order DS makes the same-wave reads below safe

        // O[e][d][a][c] += sum_b att[e,f,a,b] * v[f,d,b,c]; v hoisted over e
        #pragma unroll
        for (int gg = 0; gg < 4; ++gg) {
            const float* vb = v_l + gg * KGS + d_o * KP;
            float4 v0 = *(const float4*)(vb + 0);
            float4 v1 = *(const float4*)(vb + 4);
            float4 v2 = *(const float4*)(vb + 8);
            float4 v3 = *(const float4*)(vb + 12);
            #pragma unroll
            for (int e2 = 0; e2 < 4; ++e2) {
                const float* eb = exps_l + w * EPS_W + e2 * EPS_E + gg * 16 + half * 8;
                float4 eA = *(const float4*)(eb + 0);
                float4 eB = *(const float4*)(eb + 4);
                acc[e2][0][0] += eA.x*v0.x + eA.y*v1.x + eA.z*v2.x + eA.w*v3.x;
                acc[e2][0][1] += eA.x*v0.y + eA.y*v1.y + eA.z*v2.y + eA.w*v3.y;
                acc[e2][0][2] += eA.x*v0.z + eA.y*v1.z + eA.z*v2.z + eA.w*v3.z;
                acc[e2][0][3] += eA.x*v0.w + eA.y*v1.w + eA.z*v2.w + eA.w*v3.w;
                acc[e2][1][0] += eB.x*v0.x + eB.y*v1.x + eB.z*v2.x + eB.w*v3.x;
                acc[e2][1][1] += eB.x*v0.y + eB.y*v1.y + eB.z*v2.y + eB.w*v3.y;
                acc[e2][1][2] += eB.x*v0.z + eB.y*v1.z + eB.z*v2.z + eB.w*v3.z;
                acc[e2][1][3] += eB.x*v0.w + eB.y*v1.w + eB.z*v2.w + eB.w*v3.w;
            }
        }
    }

    // denom: sum trace over g lanes (bits 0-1); reps hold identical copies
    dtr += __shfl_xor(dtr, 1);
    dtr += __shfl_xor(dtr, 2);

    #pragma unroll
    for (int e2 = 0; e2 < 4; ++e2) {
        float den = __shfl(dtr, e2 * 4);       // lane (rep0, ee=e2, g0)
        float sO = 1.0f / (den + 1e-6f);
        int e = e0 + w * 4 + e2;
        size_t yb = (((size_t)(nn * 64 + e)) * 256 + h * 32 + d_o) * 16 + half * 8;
        *(float4*)(Y + yb)     = make_float4(acc[e2][0][0]*sO, acc[e2][0][1]*sO, acc[e2][0][2]*sO, acc[e2][0][3]*sO);
        *(float4*)(Y + yb + 4) = make_float4(acc[e2][1][0]*sO, acc[e2][1][1]*sO, acc[e2][1][2]*sO, acc[e2][1][3]*sO);
    }
}

// One block per (n,e): out = (Y @ w_out^T + inputs) * sqrt(0.5). Y lives in
// d_out; each block reads only its own slab into LDS before overwriting it.
// Tiling: thread = (pg = t&3, og = t>>2) owns p in [pg*4,+4), o in [og*4,+4).
// Per c: 1 broadcast ds_read_b128 + 1 global float4 -> 16 FMA.
__global__ __launch_bounds__(256) void k_out(const float* __restrict__ Yg,
        const float* __restrict__ woutT, const float* __restrict__ in,
        float* __restrict__ out) {
    __shared__ __align__(16) float y_l[4096];
    int b = blockIdx.x;
    int t = threadIdx.x;
    const float* src = Yg + (size_t)b * 4096;
    #pragma unroll
    for (int q = 0; q < 4; ++q)
        *(float4*)(y_l + t*16 + q*4) = *(const float4*)(src + t*16 + q*4);
    __syncthreads();

    int pg = t & 3, og = t >> 2;
    float acc[4][4];
    #pragma unroll
    for (int j = 0; j < 4; ++j)
        #pragma unroll
        for (int i = 0; i < 4; ++i) acc[j][i] = 0.f;

    #pragma unroll 2
    for (int c = 0; c < 256; ++c) {
        float4 x4 = *(const float4*)(y_l + c * 16 + pg * 4);    // broadcast
        float4 w4 = *(const float4*)(woutT + c * 256 + og * 4);
        acc[0][0] += x4.x*w4.x; acc[0][1] += x4.y*w4.x; acc[0][2] += x4.z*w4.x; acc[0][3] += x4.w*w4.x;
        acc[1][0] += x4.x*w4.y; acc[1][1] += x4.y*w4.y; acc[1][2] += x4.z*w4.y; acc[1][3] += x4.w*w4.y;
        acc[2][0] += x4.x*w4.z; acc[2][1] += x4.y*w4.z; acc[2][2] += x4.z*w4.z; acc[2][3] += x4.w*w4.z;
        acc[3][0] += x4.x*w4.w; acc[3][1] += x4.y*w4.w; acc[3][2] += x4.z*w4.w; acc[3][3] += x4.w*w4.w;
    }

    const float RS = 0.70710678118654752f;
    #pragma unroll
    for (int j = 0; j < 4; ++j) {
        int o = og * 4 + j;
        size_t ad = (size_t)b * 4096 + o * 16 + pg * 4;
        float4 i4 = *(const float4*)(in + ad);
        float4 o4;
        o4.x = (acc[j][0] + i4.x) * RS;
        o4.y = (acc[j][1] + i4.y) * RS;
        o4.z = (acc[j][2] + i4.z) * RS;
        o4.w = (acc[j][3] + i4.w) * RS;
        *(float4*)(out + ad) = o4;
    }
}

extern "C" void kernel_launch(void* const* d_in, const int* in_sizes, int n_in,
                              void* d_out, int out_size, void* d_ws, size_t ws_size,
                              hipStream_t stream) {
    const float* inputs = (const float*)d_in[0];
    const float* rmask  = (const float*)d_in[1];
    // d_in[2] = num_heads (scalar int) -- fixed at 8, unused
    const float* w_in   = (const float*)d_in[3];
    const float* w_out  = (const float*)d_in[4];
    const float* rms    = (const float*)d_in[5];

    if (ws_size < (size_t)WS_FLOATS * 4ull) return;   // need ~404 MB scratch

    float* ws    = (float*)d_ws;
    float* winT  = ws + OF_WINT;
    float* woutT = ws + OF_WOUTT;
    float* Qb    = ws + OF_Q;
    float* Kb    = ws + OF_K;
    float* Vb    = ws + OF_V;
    float* Y     = (float*)d_out;   // out_heads parked in d_out

    k_prep<<<768,  256, 0, stream>>>(w_in, w_out, winT, woutT);
    k_qkv <<<8192, 256, 0, stream>>>(inputs, winT, rms, Qb, Kb, Vb);
    k_attn<<<4096, 256, 0, stream>>>(Qb, Kb, Vb, rmask, Y);
    k_out <<<8192, 256, 0, stream>>>(Y, woutT, inputs, (float*)d_out);
}

// Round 5
// 1788.799 us; speedup vs baseline: 1.2877x; 1.2877x over previous
//
#include <hip/hip_runtime.h>
#include <math.h>

// AttentionBlock: trace-std norm -> qkv (w_in) -> per-(n,h) 4x4-block attention
// with matrix-exponential "softmax" -> w_out -> residual, all fp32.
// N=128, E=64, HID=256, L=4, NH=8, dh=32.
//
// k_attn v2: 4-phase pipeline. QK for 4 f-quads buffered in mb0..mb3; expm
// runs ONCE per lane per super-iteration (64 distinct matrices/wave) instead
// of 4x-replicated across rep lanes. attV lags 4 fg-steps (uses prev super's
// exps + lagged v staging). s-loop kept rolled (I-cache).

#define QKV_SZ   33554432u
#define OF_WINT  0u
#define OF_WOUTT 196608u
#define OF_Q     262144u
#define OF_K     (OF_Q + QKV_SZ)
#define OF_V     (OF_K + QKV_SZ)
#define WS_FLOATS (OF_V + QKV_SZ)

#define QP  20    // q_l d-stride
#define QES 656   // q_l e-stride = 32*20+16
#define KP  20    // k_l/v_l d-stride
#define KGS 648   // k_l/v_l f-stride = 32*20+8
#define EE  68    // exps e-stride
#define EP  276   // exps phase-stride (4*68+4)
#define EW  1108  // exps wave-stride (4*276+4)

__global__ __launch_bounds__(256) void k_prep(const float* __restrict__ w_in,
                                              const float* __restrict__ w_out,
                                              float* __restrict__ winT,
                                              float* __restrict__ woutT) {
    int idx = blockIdx.x * 256 + threadIdx.x;
    if (idx < 768 * 256) {
        int o = idx >> 8, c = idx & 255;
        winT[c * 768 + o] = w_in[idx];
    }
    if (idx < 256 * 256) {
        int o = idx >> 8, c = idx & 255;
        woutT[c * 256 + o] = w_out[idx];
    }
}

// Two (n,e) sites per block: fused trace-std norm + QKV projection.
// Thread (pg=t&3, og=t>>2) owns p in [pg*4,+4), o in [og*12,+12), both sites.
// Per c: 2 broadcast ds_read_b128 + 3 global float4 -> 96 FMA.
// (256,2): 96 accum VGPRs -> ~150 total; forcing 3 waves/EU risks spills.
__global__ __launch_bounds__(256, 2) void k_qkv(const float* __restrict__ in,
        const float* __restrict__ winT, const float* __restrict__ rms,
        float* __restrict__ Q, float* __restrict__ Kb, float* __restrict__ Vb) {
    __shared__ __align__(16) float x_l[2][4096];
    __shared__ float red[16];
    int b = blockIdx.x;               // sites 2b, 2b+1
    int t = threadIdx.x;
    int w = t >> 6, lane = t & 63;
    const float* src = in + (size_t)(b * 2) * 4096;

    #pragma unroll
    for (int q = 0; q < 4; ++q) {
        *(float4*)(&x_l[0][t*16 + q*4]) = *(const float4*)(src + t*16 + q*4);
        *(float4*)(&x_l[1][t*16 + q*4]) = *(const float4*)(src + 4096 + t*16 + q*4);
    }
    __syncthreads();

    float tr0 = x_l[0][t*16] + x_l[0][t*16+5] + x_l[0][t*16+10] + x_l[0][t*16+15];
    float tr1 = x_l[1][t*16] + x_l[1][t*16+5] + x_l[1][t*16+10] + x_l[1][t*16+15];
    float s0 = tr0, s1 = tr1;
    #pragma unroll
    for (int o = 1; o < 64; o <<= 1) { s0 += __shfl_xor(s0, o); s1 += __shfl_xor(s1, o); }
    if (lane == 0) { red[w] = s0; red[4 + w] = s1; }
    __syncthreads();
    float mean0 = (red[0] + red[1] + red[2] + red[3]) * (1.0f / 256.0f);
    float mean1 = (red[4] + red[5] + red[6] + red[7]) * (1.0f / 256.0f);
    float d0 = tr0 - mean0; d0 *= d0;
    float d1 = tr1 - mean1; d1 *= d1;
    #pragma unroll
    for (int o = 1; o < 64; o <<= 1) { d0 += __shfl_xor(d0, o); d1 += __shfl_xor(d1, o); }
    if (lane == 0) { red[8 + w] = d0; red[12 + w] = d1; }
    __syncthreads();
    float var0 = (red[8] + red[9] + red[10] + red[11]) * (1.0f / 255.0f);
    float var1 = (red[12] + red[13] + red[14] + red[15]) * (1.0f / 255.0f);
    float rv = rms[t];
    float sc0 = rv / (sqrtf(var0) + 1e-8f);
    float sc1 = rv / (sqrtf(var1) + 1e-8f);

    #pragma unroll
    for (int q = 0; q < 4; ++q) {
        float4 v4 = *(float4*)(&x_l[0][t*16 + q*4]);
        v4.x *= sc0; v4.y *= sc0; v4.z *= sc0; v4.w *= sc0;
        *(float4*)(&x_l[0][t*16 + q*4]) = v4;
        float4 u4 = *(float4*)(&x_l[1][t*16 + q*4]);
        u4.x *= sc1; u4.y *= sc1; u4.z *= sc1; u4.w *= sc1;
        *(float4*)(&x_l[1][t*16 + q*4]) = u4;
    }
    __syncthreads();

    int pg = t & 3, og = t >> 2;
    float a0[12][4], a1[12][4];
    #pragma unroll
    for (int j = 0; j < 12; ++j)
        #pragma unroll
        for (int i = 0; i < 4; ++i) { a0[j][i] = 0.f; a1[j][i] = 0.f; }

    const float* wrow = winT + og * 12;
    #pragma unroll 2
    for (int c = 0; c < 256; ++c) {
        float wv[12];
        *(float4*)(wv + 0) = *(const float4*)(wrow + c * 768 + 0);
        *(float4*)(wv + 4) = *(const float4*)(wrow + c * 768 + 4);
        *(float4*)(wv + 8) = *(const float4*)(wrow + c * 768 + 8);
        float4 x0 = *(const float4*)(&x_l[0][c * 16 + pg * 4]);
        float4 x1 = *(const float4*)(&x_l[1][c * 16 + pg * 4]);
        #pragma unroll
        for (int j = 0; j < 12; ++j) {
            float wj = wv[j];
            a0[j][0] += x0.x * wj; a0[j][1] += x0.y * wj;
            a0[j][2] += x0.z * wj; a0[j][3] += x0.w * wj;
            a1[j][0] += x1.x * wj; a1[j][1] += x1.y * wj;
            a1[j][2] += x1.z * wj; a1[j][3] += x1.w * wj;
        }
    }

    #pragma unroll
    for (int si = 0; si < 2; ++si) {
        int site = b * 2 + si;
        int nn = site >> 6, e = site & 63;
        #pragma unroll
        for (int j = 0; j < 12; ++j) {
            int o = og * 12 + j;
            int buf = o >> 8, co = o & 255;
            int h = co >> 5, d = co & 31;
            float* dst = (buf == 0) ? Q : (buf == 1) ? Kb : Vb;
            size_t ad = (((size_t)(nn * 8 + h)) * 64 + e) * 512 + d * 16 + pg * 4;
            const float (*ac)[4] = si ? a1 : a0;
            *(float4*)(dst + ad) = make_float4(ac[j][0], ac[j][1], ac[j][2], ac[j][3]);
        }
    }
}

// attV for phase P_ (runtime ok): O[e][d][a][c] += sum_b exps[e,P_,gg,a,b]*v[gg,d,b,c]
#define ATTV(P_)                                                              \
    {                                                                         \
        _Pragma("unroll 2")                                                   \
        for (int gg = 0; gg < 4; ++gg) {                                      \
            const float* vb = v_l + gg * KGS + d_o * KP;                      \
            float4 v0 = *(const float4*)(vb + 0);                             \
            float4 v1 = *(const float4*)(vb + 4);                             \
            float4 v2 = *(const float4*)(vb + 8);                             \
            float4 v3 = *(const float4*)(vb + 12);                            \
            _Pragma("unroll")                                                 \
            for (int e2 = 0; e2 < 4; ++e2) {                                  \
                const float* eb = exps_l + w * EW + (P_) * EP + e2 * EE + gg * 16 + half * 8; \
                float4 eA = *(const float4*)(eb + 0);                         \
                float4 eB = *(const float4*)(eb + 4);                         \
                acc[e2][0][0] += eA.x*v0.x + eA.y*v1.x + eA.z*v2.x + eA.w*v3.x; \
                acc[e2][0][1] += eA.x*v0.y + eA.y*v1.y + eA.z*v2.y + eA.w*v3.y; \
                acc[e2][0][2] += eA.x*v0.z + eA.y*v1.z + eA.z*v2.z + eA.w*v3.z; \
                acc[e2][0][3] += eA.x*v0.w + eA.y*v1.w + eA.z*v2.w + eA.w*v3.w; \
                acc[e2][1][0] += eB.x*v0.x + eB.y*v1.x + eB.z*v2.x + eB.w*v3.x; \
                acc[e2][1][1] += eB.x*v0.y + eB.y*v1.y + eB.z*v2.y + eB.w*v3.y; \
                acc[e2][1][2] += eB.x*v0.z + eB.y*v1.z + eB.z*v2.z + eB.w*v3.z; \
                acc[e2][1][3] += eB.x*v0.w + eB.y*v1.w + eB.z*v2.w + eB.w*v3.w; \
            }                                                                 \
        }                                                                     \
    }

// One pipeline phase: stage k(fg)/v(fg-4), prefetch k(fg+1)/v(fg-3),
// QK(fg) -> MB (static reg array), attV(fg-4).
#define QK_PHASE(P, MB)                                                       \
    {                                                                         \
        const int fg = s * 4 + (P);                                           \
        __syncthreads();                                                      \
        _Pragma("unroll")                                                     \
        for (int r = 0; r < 2; ++r) {                                         \
            *(float4*)(k_l + sld[r]) = pk[r];                                 \
            if (fg >= 4) *(float4*)(v_l + sld[r]) = pv[r];                    \
        }                                                                     \
        __syncthreads();                                                      \
        if (fg < 15) {                                                        \
            _Pragma("unroll")                                                 \
            for (int r = 0; r < 2; ++r)                                       \
                pk[r] = *(const float4*)(Kg + nhbase + (size_t)(fg + 1) * 2048 + sgo[r]); \
        }                                                                     \
        if (fg >= 3) {                                                        \
            _Pragma("unroll")                                                 \
            for (int r = 0; r < 2; ++r)                                       \
                pv[r] = *(const float4*)(Vg + nhbase + (size_t)(fg - 3) * 2048 + sgo[r]); \
        }                                                                     \
        _Pragma("unroll")                                                     \
        for (int t = 0; t < 16; ++t) MB[t] = 0.f;                             \
        {                                                                     \
            const float* kp = k_l + g * KGS + rep * KP;                       \
            _Pragma("unroll 2")                                               \
            for (int dd = 0; dd < 8; ++dd) {                                  \
                float qa[16], kb[16];                                         \
                const float* qd = qp0 + dd * (4 * QP);                        \
                const float* kd = kp + dd * (4 * KP);                         \
                *(float4*)(qa + 0)  = *(const float4*)(qd + 0);               \
                *(float4*)(qa + 4)  = *(const float4*)(qd + 4);               \
                *(float4*)(qa + 8)  = *(const float4*)(qd + 8);               \
                *(float4*)(qa + 12) = *(const float4*)(qd + 12);              \
                *(float4*)(kb + 0)  = *(const float4*)(kd + 0);               \
                *(float4*)(kb + 4)  = *(const float4*)(kd + 4);               \
                *(float4*)(kb + 8)  = *(const float4*)(kd + 8);               \
                *(float4*)(kb + 12) = *(const float4*)(kd + 12);              \
                _Pragma("unroll")                                             \
                for (int a = 0; a < 4; ++a)                                   \
                    _Pragma("unroll")                                         \
                    for (int bb = 0; bb < 4; ++bb)                            \
                        _Pragma("unroll")                                     \
                        for (int c = 0; c < 4; ++c)                           \
                            MB[a*4+c] += qa[a*4+bb] * kb[bb*4+c];             \
            }                                                                 \
        }                                                                     \
        _Pragma("unroll")                                                     \
        for (int t = 0; t < 16; ++t) {                                        \
            MB[t] += __shfl_xor(MB[t], 16);                                   \
            MB[t] += __shfl_xor(MB[t], 32);                                   \
        }                                                                     \
        if (fg >= 4) ATTV(P);                                                 \
    }

__global__ __launch_bounds__(256, 2) void k_attn(const float* __restrict__ Q,
        const float* __restrict__ Kg, const float* __restrict__ Vg,
        const float* __restrict__ rmask, float* __restrict__ Y) {
    __shared__ __align__(16) float q_l[16 * QES];   // 41 KB
    __shared__ __align__(16) float k_l[4 * KGS];    // 10.1 KB
    __shared__ __align__(16) float v_l[4 * KGS];    // 10.1 KB
    __shared__ __align__(16) float exps_l[4 * EW];  // 17.3 KB -> 80.4 KB total, 2 blk/CU

    int lb = ((blockIdx.x & 7) << 9) | (blockIdx.x >> 3);   // XCD-contig remap
    int eq = lb & 3, h = (lb >> 2) & 7, nn = lb >> 5;
    int tid = threadIdx.x;
    int w = tid >> 6, lane = tid & 63;
    size_t nhbase = ((size_t)(nn * 8 + h)) * (64 * 512);
    int e0 = eq * 16;

    const float rsq = 0.17677669529663687f;  // 1/sqrt(32)

    #pragma unroll
    for (int r = 0; r < 8; ++r) {            // stage q (pre-scaled)
        int idx = r * 256 + tid;
        int ee_ = idx >> 7, rem = idx & 127;
        int d = rem >> 2, c4 = rem & 3;
        float4 v4 = *(const float4*)(Q + nhbase + (size_t)(e0 + ee_) * 512 + d * 16 + c4 * 4);
        v4.x *= rsq; v4.y *= rsq; v4.z *= rsq; v4.w *= rsq;
        *(float4*)(q_l + ee_ * QES + d * QP + c4 * 4) = v4;
    }

    int rep = lane >> 4, ee = (lane >> 2) & 3, g = lane & 3;
    int eL = w * 4 + ee;
    int d_o = lane & 31, half = lane >> 5;
    const float* qp0 = q_l + eL * QES + rep * QP;

    int sld[2]; size_t sgo[2];
    #pragma unroll
    for (int r = 0; r < 2; ++r) {
        int slot = r * 256 + tid;
        int gg = slot >> 7, rem = slot & 127;
        int d = rem >> 2, c4 = rem & 3;
        sld[r] = gg * KGS + d * KP + c4 * 4;
        sgo[r] = (size_t)(gg * 512 + d * 16 + c4 * 4);
    }

    float acc[4][2][4];
    #pragma unroll
    for (int a = 0; a < 4; ++a)
        #pragma unroll
        for (int x = 0; x < 2; ++x)
            #pragma unroll
            for (int c = 0; c < 4; ++c) acc[a][x][c] = 0.f;
    float dtr = 0.f;

    float mb0[16], mb1[16], mb2[16], mb3[16];
    float4 pk[2], pv[2];
    #pragma unroll
    for (int r = 0; r < 2; ++r)              // prologue: k(0)
        pk[r] = *(const float4*)(Kg + nhbase + sgo[r]);

    #pragma unroll 1                          // keep rolled: body ~3.5K instr (I-cache)
    for (int s = 0; s < 4; ++s) {
        QK_PHASE(0, mb0)
        QK_PHASE(1, mb1)
        QK_PHASE(2, mb2)
        QK_PHASE(3, mb3)

        // ---- expm: each lane exponentiates phase-'rep' matrix (distinct) ----
        float mm[16];
        #pragma unroll
        for (int t = 0; t < 16; ++t)
            mm[t] = (rep == 0) ? mb0[t] : (rep == 1) ? mb1[t] : (rep == 2) ? mb2[t] : mb3[t];

        float r0 = fabsf(mm[0])  + fabsf(mm[1])  + fabsf(mm[2])  + fabsf(mm[3]);
        float r1 = fabsf(mm[4])  + fabsf(mm[5])  + fabsf(mm[6])  + fabsf(mm[7]);
        float r2 = fabsf(mm[8])  + fabsf(mm[9])  + fabsf(mm[10]) + fabsf(mm[11]);
        float r3 = fabsf(mm[12]) + fabsf(mm[13]) + fabsf(mm[14]) + fabsf(mm[15]);
        float nrm = fmaxf(fmaxf(r0, r1), fmaxf(r2, r3));
        int sq = 0;
        if (nrm > 0.5f) {
            sq = (int)ceilf(log2f(nrm)) + 1;
            if (sq < 0) sq = 0;
        }
        float sc2 = exp2f((float)(-sq));
        #pragma unroll
        for (int t = 0; t < 16; ++t) mm[t] *= sc2;
        float p[16];
        #pragma unroll
        for (int t = 0; t < 16; ++t) p[t] = 0.f;
        p[0] = p[5] = p[10] = p[15] = 1.f;
        #pragma unroll
        for (int tt = 8; tt >= 1; --tt) {
            float np[16];
            float rr = 1.0f / (float)tt;
            #pragma unroll
            for (int i = 0; i < 4; ++i)
                #pragma unroll
                for (int j = 0; j < 4; ++j) {
                    float s2 = mm[i*4+0]*p[j] + mm[i*4+1]*p[4+j] + mm[i*4+2]*p[8+j] + mm[i*4+3]*p[12+j];
                    np[i*4+j] = ((i == j) ? 1.0f : 0.0f) + s2 * rr;
                }
            #pragma unroll
            for (int t = 0; t < 16; ++t) p[t] = np[t];
        }
        #pragma unroll 1
        for (int it = 0; it < sq; ++it) {
            float np[16];
            #pragma unroll
            for (int i = 0; i < 4; ++i)
                #pragma unroll
                for (int j = 0; j < 4; ++j)
                    np[i*4+j] = p[i*4+0]*p[j] + p[i*4+1]*p[4+j] + p[i*4+2]*p[8+j] + p[i*4+3]*p[12+j];
            #pragma unroll
            for (int t = 0; t < 16; ++t) p[t] = np[t];
        }

        dtr += p[0] + p[5] + p[10] + p[15];   // pre-mask trace

        float mk = rmask[nn * 64 + s * 16 + rep * 4 + g];
        float* eb = exps_l + w * EW + rep * EP + ee * EE + g * 16;
        *(float4*)(eb + 0)  = make_float4(p[0]*mk,  p[1]*mk,  p[2]*mk,  p[3]*mk);
        *(float4*)(eb + 4)  = make_float4(p[4]*mk,  p[5]*mk,  p[6]*mk,  p[7]*mk);
        *(float4*)(eb + 8)  = make_float4(p[8]*mk,  p[9]*mk,  p[10]*mk, p[11]*mk);
        *(float4*)(eb + 12) = make_float4(p[12]*mk, p[13]*mk, p[14]*mk, p[15]*mk);
        // same-wave DS in-order: these writes complete before next super's
        // ATTV reads (same wave, w-private region)
    }

    // epilogue: 4 lagged attV steps (v(12..15), exps of super 3)
    #pragma unroll 1
    for (int ep = 0; ep < 4; ++ep) {
        __syncthreads();
        #pragma unroll
        for (int r = 0; r < 2; ++r)
            *(float4*)(v_l + sld[r]) = pv[r];
        __syncthreads();
        if (ep < 3) {
            #pragma unroll
            for (int r = 0; r < 2; ++r)
                pv[r] = *(const float4*)(Vg + nhbase + (size_t)(13 + ep) * 2048 + sgo[r]);
        }
        ATTV(ep)
    }

    // denom: reduce trace over g (bits 0-1) and phase/rep (bits 4-5)
    dtr += __shfl_xor(dtr, 1);
    dtr += __shfl_xor(dtr, 2);
    dtr += __shfl_xor(dtr, 16);
    dtr += __shfl_xor(dtr, 32);

    #pragma unroll
    for (int e2 = 0; e2 < 4; ++e2) {
        float den = __shfl(dtr, e2 * 4);
        float sO = 1.0f / (den + 1e-6f);
        int e = e0 + w * 4 + e2;
        size_t yb = (((size_t)(nn * 64 + e)) * 256 + h * 32 + d_o) * 16 + half * 8;
        *(float4*)(Y + yb)     = make_float4(acc[e2][0][0]*sO, acc[e2][0][1]*sO, acc[e2][0][2]*sO, acc[e2][0][3]*sO);
        *(float4*)(Y + yb + 4) = make_float4(acc[e2][1][0]*sO, acc[e2][1][1]*sO, acc[e2][1][2]*sO, acc[e2][1][3]*sO);
    }
}

// Two sites per block: out = (Y @ w_out^T + inputs) * sqrt(0.5).
__global__ __launch_bounds__(256, 4) void k_out(const float* __restrict__ Yg,
        const float* __restrict__ woutT, const float* __restrict__ in,
        float* __restrict__ out) {
    __shared__ __align__(16) float y_l[2][4096];
    int b = blockIdx.x;
    int t = threadIdx.x;
    const float* src = Yg + (size_t)(b * 2) * 4096;
    #pragma unroll
    for (int q = 0; q < 4; ++q) {
        *(float4*)(&y_l[0][t*16 + q*4]) = *(const float4*)(src + t*16 + q*4);
        *(float4*)(&y_l[1][t*16 + q*4]) = *(const float4*)(src + 4096 + t*16 + q*4);
    }
    __syncthreads();

    int pg = t & 3, og = t >> 2;
    float a0[4][4], a1[4][4];
    #pragma unroll
    for (int j = 0; j < 4; ++j)
        #pragma unroll
        for (int i = 0; i < 4; ++i) { a0[j][i] = 0.f; a1[j][i] = 0.f; }

    #pragma unroll 2
    for (int c = 0; c < 256; ++c) {
        float4 w4 = *(const float4*)(woutT + c * 256 + og * 4);
        float4 x0 = *(const float4*)(&y_l[0][c * 16 + pg * 4]);
        float4 x1 = *(const float4*)(&y_l[1][c * 16 + pg * 4]);
        a0[0][0] += x0.x*w4.x; a0[0][1] += x0.y*w4.x; a0[0][2] += x0.z*w4.x; a0[0][3] += x0.w*w4.x;
        a0[1][0] += x0.x*w4.y; a0[1][1] += x0.y*w4.y; a0[1][2] += x0.z*w4.y; a0[1][3] += x0.w*w4.y;
        a0[2][0] += x0.x*w4.z; a0[2][1] += x0.y*w4.z; a0[2][2] += x0.z*w4.z; a0[2][3] += x0.w*w4.z;
        a0[3][0] += x0.x*w4.w; a0[3][1] += x0.y*w4.w; a0[3][2] += x0.z*w4.w; a0[3][3] += x0.w*w4.w;
        a1[0][0] += x1.x*w4.x; a1[0][1] += x1.y*w4.x; a1[0][2] += x1.z*w4.x; a1[0][3] += x1.w*w4.x;
        a1[1][0] += x1.x*w4.y; a1[1][1] += x1.y*w4.y; a1[1][2] += x1.z*w4.y; a1[1][3] += x1.w*w4.y;
        a1[2][0] += x1.x*w4.z; a1[2][1] += x1.y*w4.z; a1[2][2] += x1.z*w4.z; a1[2][3] += x1.w*w4.z;
        a1[3][0] += x1.x*w4.w; a1[3][1] += x1.y*w4.w; a1[3][2] += x1.z*w4.w; a1[3][3] += x1.w*w4.w;
    }

    const float RS = 0.70710678118654752f;
    #pragma unroll
    for (int si = 0; si < 2; ++si) {
        const float (*ac)[4] = si ? a1 : a0;
        #pragma unroll
        for (int j = 0; j < 4; ++j) {
            int o = og * 4 + j;
            size_t ad = (size_t)(b * 2 + si) * 4096 + o * 16 + pg * 4;
            float4 i4 = *(const float4*)(in + ad);
            float4 o4;
            o4.x = (ac[j][0] + i4.x) * RS;
            o4.y = (ac[j][1] + i4.y) * RS;
            o4.z = (ac[j][2] + i4.z) * RS;
            o4.w = (ac[j][3] + i4.w) * RS;
            *(float4*)(out + ad) = o4;
        }
    }
}

extern "C" void kernel_launch(void* const* d_in, const int* in_sizes, int n_in,
                              void* d_out, int out_size, void* d_ws, size_t ws_size,
                              hipStream_t stream) {
    const float* inputs = (const float*)d_in[0];
    const float* rmask  = (const float*)d_in[1];
    // d_in[2] = num_heads (scalar int) -- fixed at 8, unused
    const float* w_in   = (const float*)d_in[3];
    const float* w_out  = (const float*)d_in[4];
    const float* rms    = (const float*)d_in[5];

    if (ws_size < (size_t)WS_FLOATS * 4ull) return;   // need ~404 MB scratch

    float* ws    = (float*)d_ws;
    float* winT  = ws + OF_WINT;
    float* woutT = ws + OF_WOUTT;
    float* Qb    = ws + OF_Q;
    float* Kb    = ws + OF_K;
    float* Vb    = ws + OF_V;
    float* Y     = (float*)d_out;   // out_heads parked in d_out

    k_prep<<<768,  256, 0, stream>>>(w_in, w_out, winT, woutT);
    k_qkv <<<4096, 256, 0, stream>>>(inputs, winT, rms, Qb, Kb, Vb);
    k_attn<<<4096, 256, 0, stream>>>(Qb, Kb, Vb, rmask, Y);
    k_out <<<4096, 256, 0, stream>>>(Y, woutT, inputs, (float*)d_out);
}